// Round 1
// baseline (1528.223 us; speedup 1.0000x reference)
//
#include <hip/hip_runtime.h>

// GCNConv + ReLU + global mean pool for MI355X (gfx950).
// Reference: deg = segsum(w, col)+1(self); dinv=rsqrt(deg);
// h = x@W; out[i] = relu(sum_{e: col=i} dinv[row]dinv[col]w[e] h[row] + dinv[i]^2 h[i] + b)
// pool[g] = mean over batch==g of out.

__global__ __launch_bounds__(256) void k_init_deg(float* deg, int N) {
    int i = blockIdx.x * 256 + threadIdx.x;
    if (i < N) deg[i] = 1.0f;   // self-loop weight
}

__global__ __launch_bounds__(256) void k_deg_scatter(const int* __restrict__ ei,
                                                     const float* __restrict__ ew,
                                                     float* deg, int E) {
    int e = blockIdx.x * 256 + threadIdx.x;
    if (e < E) atomicAdd(&deg[ei[E + e]], ew[e]);   // col = target
}

__global__ __launch_bounds__(256) void k_dinv(float* deg, int N) {
    int i = blockIdx.x * 256 + threadIdx.x;
    if (i < N) {
        float d = deg[i];
        deg[i] = d > 0.f ? rsqrtf(d) : 0.f;
    }
}

// h = x @ W : (N x 128) @ (128 x 128)
// Block: 256 threads, 64 rows per block. W (64KB) + padded x tile (33.8KB) in LDS.
// Thread (tr = t&15, tc = t>>4): computes rows {tr,tr+16,tr+32,tr+48} x dims [tc*8, tc*8+8).
// x tile padded to stride 132 -> 2-way (free) LDS conflicts; W reads conflict-free by tc grouping.
__global__ __launch_bounds__(256) void k_gemm(const float* __restrict__ x,
                                              const float* __restrict__ W,
                                              float* __restrict__ h, int N) {
    __shared__ float sW[128 * 128];
    __shared__ float sX[64 * 132];
    int t = threadIdx.x;
    for (int i = t; i < 128 * 128 / 4; i += 256)
        ((float4*)sW)[i] = ((const float4*)W)[i];
    int row0 = blockIdx.x * 64;
    int nrows = min(64, N - row0);
    for (int i = t; i < nrows * 32; i += 256) {
        int r = i >> 5, kq = i & 31;
        *(float4*)&sX[r * 132 + kq * 4] = ((const float4*)(x + (size_t)row0 * 128))[i];
    }
    __syncthreads();
    int tr = t & 15;
    int d0 = (t >> 4) * 8;
    float acc[4][8];
#pragma unroll
    for (int r = 0; r < 4; ++r)
#pragma unroll
        for (int d = 0; d < 8; ++d) acc[r][d] = 0.f;

    for (int k = 0; k < 128; k += 4) {
        float4 wv[4][2];
#pragma unroll
        for (int j = 0; j < 4; ++j) {
            wv[j][0] = *(float4*)&sW[(k + j) * 128 + d0];
            wv[j][1] = *(float4*)&sW[(k + j) * 128 + d0 + 4];
        }
#pragma unroll
        for (int rr = 0; rr < 4; ++rr) {
            float4 xv = *(float4*)&sX[(tr + 16 * rr) * 132 + k];
            float xs[4] = {xv.x, xv.y, xv.z, xv.w};
#pragma unroll
            for (int j = 0; j < 4; ++j) {
                const float* wp = (const float*)&wv[j][0];
#pragma unroll
                for (int d = 0; d < 8; ++d)
                    acc[rr][d] = fmaf(xs[j], wp[d], acc[rr][d]);
            }
        }
    }
#pragma unroll
    for (int rr = 0; rr < 4; ++rr) {
        int rg = row0 + tr + 16 * rr;
        if (rg < N) {
            float4 o0 = make_float4(acc[rr][0], acc[rr][1], acc[rr][2], acc[rr][3]);
            float4 o1 = make_float4(acc[rr][4], acc[rr][5], acc[rr][6], acc[rr][7]);
            *(float4*)&h[(size_t)rg * 128 + d0] = o0;
            *(float4*)&h[(size_t)rg * 128 + d0 + 4] = o1;
        }
    }
}

// 32 threads per edge, 4 dims each (float4 gather + 4 scalar f32 atomics).
__global__ __launch_bounds__(256) void k_edge_scatter(const int* __restrict__ ei,
                                                      const float* __restrict__ ew,
                                                      const float* __restrict__ dinv,
                                                      const float* __restrict__ h,
                                                      float* out, int E) {
    int gid = blockIdx.x * 256 + threadIdx.x;
    int e = gid >> 5;
    if (e >= E) return;
    int lane = gid & 31;
    int row = ei[e];
    int col = ei[E + e];
    float norm = dinv[row] * dinv[col] * ew[e];
    float4 hv = *(const float4*)&h[(size_t)row * 128 + lane * 4];
    float* o = &out[(size_t)col * 128 + lane * 4];
    atomicAdd(o + 0, hv.x * norm);
    atomicAdd(o + 1, hv.y * norm);
    atomicAdd(o + 2, hv.z * norm);
    atomicAdd(o + 3, hv.w * norm);
}

__global__ __launch_bounds__(256) void k_count(const int* __restrict__ batch, float* cnt, int N) {
    int i = blockIdx.x * 256 + threadIdx.x;
    if (i < N) atomicAdd(&cnt[batch[i]], 1.0f);
}

// out = relu(acc + dinv^2 * h + b); pool[batch[i]] += out
__global__ __launch_bounds__(256) void k_finalize(float* out, const float* __restrict__ h,
                                                  const float* __restrict__ dinv,
                                                  const float* __restrict__ b,
                                                  const int* __restrict__ batch,
                                                  float* pool, int N) {
    int gid = blockIdx.x * 256 + threadIdx.x;
    if (gid >= N * 128) return;
    int i = gid >> 7;
    int d = gid & 127;
    float di = dinv[i];
    float v = out[gid] + h[gid] * di * di + b[d];
    v = fmaxf(v, 0.f);
    out[gid] = v;
    atomicAdd(&pool[(size_t)batch[i] * 128 + d], v);
}

__global__ __launch_bounds__(256) void k_pool_div(float* pool, const float* __restrict__ cnt, int G) {
    int gid = blockIdx.x * 256 + threadIdx.x;
    if (gid >= G * 128) return;
    int g = gid >> 7;
    pool[gid] /= fmaxf(cnt[g], 1.0f);
}

extern "C" void kernel_launch(void* const* d_in, const int* in_sizes, int n_in,
                              void* d_out, int out_size, void* d_ws, size_t ws_size,
                              hipStream_t stream) {
    const float* x     = (const float*)d_in[0];
    const int*   ei    = (const int*)d_in[1];
    const float* ew    = (const float*)d_in[2];
    const int*   batch = (const int*)d_in[3];
    const float* W     = (const float*)d_in[4];
    const float* b     = (const float*)d_in[5];

    int N = in_sizes[3];        // 50000
    int E = in_sizes[2];        // 800000
    int G = (out_size - N * 128) / 128;   // 500

    float* out  = (float*)d_out;
    float* pool = out + (size_t)N * 128;

    float* h   = (float*)d_ws;                 // N*128 floats
    float* deg = h + (size_t)N * 128;          // N floats (becomes dinv)
    float* cnt = deg + N;                      // G floats

    hipMemsetAsync(d_out, 0, (size_t)out_size * sizeof(float), stream);
    hipMemsetAsync(cnt, 0, (size_t)G * sizeof(float), stream);

    k_init_deg<<<(N + 255) / 256, 256, 0, stream>>>(deg, N);
    k_deg_scatter<<<(E + 255) / 256, 256, 0, stream>>>(ei, ew, deg, E);
    k_dinv<<<(N + 255) / 256, 256, 0, stream>>>(deg, N);
    k_gemm<<<(N + 63) / 64, 256, 0, stream>>>(x, W, h, N);
    k_edge_scatter<<<(E * 32 + 255) / 256, 256, 0, stream>>>(ei, ew, deg, h, out, E);
    k_count<<<(N + 255) / 256, 256, 0, stream>>>(batch, cnt, N);
    k_finalize<<<((N * 128) + 255) / 256, 256, 0, stream>>>(out, h, deg, b, batch, pool, N);
    k_pool_div<<<(G * 128 + 255) / 256, 256, 0, stream>>>(pool, cnt, G);
}

// Round 2
// 378.120 us; speedup vs baseline: 4.0416x; 4.0416x over previous
//
#include <hip/hip_runtime.h>

// GCNConv + ReLU + global mean pool for MI355X (gfx950).
// Round 2: replace 102M-float-atomic edge scatter (1340us, atomic-throughput
// bound) with on-device CSR-by-target build + per-node wave gather.

// ---------- degree / norm ----------

__global__ __launch_bounds__(256) void k_init_deg(float* deg, int N) {
    int i = blockIdx.x * 256 + threadIdx.x;
    if (i < N) deg[i] = 1.0f;   // self-loop weight
}

// deg[col] += w  AND  cnti[col] += 1 (in-degree count for CSR)
__global__ __launch_bounds__(256) void k_deg_count(const int* __restrict__ ei,
                                                   const float* __restrict__ ew,
                                                   float* deg, int* cnti, int E) {
    int e = blockIdx.x * 256 + threadIdx.x;
    if (e < E) {
        int col = ei[E + e];
        atomicAdd(&deg[col], ew[e]);
        atomicAdd(&cnti[col], 1);
    }
}

__global__ __launch_bounds__(256) void k_dinv(float* deg, int N) {
    int i = blockIdx.x * 256 + threadIdx.x;
    if (i < N) {
        float d = deg[i];
        deg[i] = d > 0.f ? rsqrtf(d) : 0.f;
    }
}

// ---------- single-block exclusive scan: cnti[0..N) -> rowptr[0..N] ----------
__global__ __launch_bounds__(1024) void k_scan(const int* __restrict__ cnti,
                                               int* __restrict__ rowptr, int N) {
    __shared__ int warp_sums[16];
    __shared__ int carry;
    int t = threadIdx.x;
    if (t == 0) carry = 0;
    __syncthreads();
    int lane = t & 63, wid = t >> 6;
    for (int base = 0; base < N; base += 1024) {
        int i = base + t;
        int v = (i < N) ? cnti[i] : 0;
        int s = v;
#pragma unroll
        for (int o = 1; o < 64; o <<= 1) {
            int u = __shfl_up(s, o);
            if (lane >= o) s += u;
        }
        if (lane == 63) warp_sums[wid] = s;
        __syncthreads();
        if (wid == 0) {
            int ws = (lane < 16) ? warp_sums[lane] : 0;
#pragma unroll
            for (int o = 1; o < 16; o <<= 1) {
                int u = __shfl_up(ws, o);
                if (lane >= o) ws += u;
            }
            if (lane < 16) warp_sums[lane] = ws;
        }
        __syncthreads();
        int woff = (wid == 0) ? 0 : warp_sums[wid - 1];
        if (i < N) rowptr[i] = carry + woff + (s - v);   // exclusive
        __syncthreads();
        if (t == 0) carry += warp_sums[15];
        __syncthreads();
    }
    if (t == 0) rowptr[N] = carry;
}

// ---------- bucket fill: srcval[pos] = (src row, norm) ----------
__global__ __launch_bounds__(256) void k_fill(const int* __restrict__ ei,
                                              const float* __restrict__ ew,
                                              const float* __restrict__ dinv,
                                              const int* __restrict__ rowptr,
                                              int* __restrict__ fill,
                                              int2* __restrict__ srcval, int E) {
    int e = blockIdx.x * 256 + threadIdx.x;
    if (e >= E) return;
    int row = ei[e];
    int col = ei[E + e];
    float norm = dinv[row] * dinv[col] * ew[e];
    int pos = rowptr[col] + atomicAdd(&fill[col], 1);
    srcval[pos] = make_int2(row, __float_as_int(norm));
}

// ---------- h = x @ W : (N x 128) @ (128 x 128) ----------
__global__ __launch_bounds__(256) void k_gemm(const float* __restrict__ x,
                                              const float* __restrict__ W,
                                              float* __restrict__ h, int N) {
    __shared__ float sW[128 * 128];
    __shared__ float sX[64 * 132];
    int t = threadIdx.x;
    for (int i = t; i < 128 * 128 / 4; i += 256)
        ((float4*)sW)[i] = ((const float4*)W)[i];
    int row0 = blockIdx.x * 64;
    int nrows = min(64, N - row0);
    for (int i = t; i < nrows * 32; i += 256) {
        int r = i >> 5, kq = i & 31;
        *(float4*)&sX[r * 132 + kq * 4] = ((const float4*)(x + (size_t)row0 * 128))[i];
    }
    __syncthreads();
    int tr = t & 15;
    int d0 = (t >> 4) * 8;
    float acc[4][8];
#pragma unroll
    for (int r = 0; r < 4; ++r)
#pragma unroll
        for (int d = 0; d < 8; ++d) acc[r][d] = 0.f;

    for (int k = 0; k < 128; k += 4) {
        float4 wv[4][2];
#pragma unroll
        for (int j = 0; j < 4; ++j) {
            wv[j][0] = *(float4*)&sW[(k + j) * 128 + d0];
            wv[j][1] = *(float4*)&sW[(k + j) * 128 + d0 + 4];
        }
#pragma unroll
        for (int rr = 0; rr < 4; ++rr) {
            float4 xv = *(float4*)&sX[(tr + 16 * rr) * 132 + k];
            float xs[4] = {xv.x, xv.y, xv.z, xv.w};
#pragma unroll
            for (int j = 0; j < 4; ++j) {
                const float* wp = (const float*)&wv[j][0];
#pragma unroll
                for (int d = 0; d < 8; ++d)
                    acc[rr][d] = fmaf(xs[j], wp[d], acc[rr][d]);
            }
        }
    }
#pragma unroll
    for (int rr = 0; rr < 4; ++rr) {
        int rg = row0 + tr + 16 * rr;
        if (rg < N) {
            float4 o0 = make_float4(acc[rr][0], acc[rr][1], acc[rr][2], acc[rr][3]);
            float4 o1 = make_float4(acc[rr][4], acc[rr][5], acc[rr][6], acc[rr][7]);
            *(float4*)&h[(size_t)rg * 128 + d0] = o0;
            *(float4*)&h[(size_t)rg * 128 + d0 + 4] = o1;
        }
    }
}

// ---------- gather-aggregate: 1 wave per node, 2 dims per lane ----------
// out[i] = relu( sum_j srcval * h[src] + dinv[i]^2*h[i] + b )
__global__ __launch_bounds__(256) void k_aggregate(const int2* __restrict__ srcval,
                                                   const int* __restrict__ rowptr,
                                                   const float* __restrict__ h,
                                                   const float* __restrict__ dinv,
                                                   const float* __restrict__ b,
                                                   float* __restrict__ out, int N) {
    int node = blockIdx.x * 4 + (threadIdx.x >> 6);
    if (node >= N) return;
    int lane = threadIdx.x & 63;
    int beg = rowptr[node], end = rowptr[node + 1];
    float2 acc = make_float2(0.f, 0.f);
    int j = beg;
    int2 sv = (j < end) ? srcval[j] : make_int2(0, 0);
    while (j < end) {
        int2 cur = sv;
        if (j + 1 < end) sv = srcval[j + 1];          // prefetch next edge meta
        float nrm = __int_as_float(cur.y);
        float2 hv = *(const float2*)&h[(size_t)cur.x * 128 + lane * 2];
        acc.x = fmaf(hv.x, nrm, acc.x);
        acc.y = fmaf(hv.y, nrm, acc.y);
        ++j;
    }
    float di = dinv[node];
    float s = di * di;
    float2 hs = *(const float2*)&h[(size_t)node * 128 + lane * 2];
    float2 bv = *(const float2*)&b[lane * 2];
    float2 v;
    v.x = fmaxf(fmaf(hs.x, s, acc.x) + bv.x, 0.f);
    v.y = fmaxf(fmaf(hs.y, s, acc.y) + bv.y, 0.f);
    *(float2*)&out[(size_t)node * 128 + lane * 2] = v;
}

// ---------- pool: batch is sorted -> segmented running sums ----------
__global__ __launch_bounds__(256) void k_pool(const float* __restrict__ out,
                                              const int* __restrict__ batch,
                                              float* pool, int N) {
    int n0 = blockIdx.x * 128;
    int d = threadIdx.x & 127;
    int r = threadIdx.x >> 7;          // 0 or 1
    float acc = 0.f;
    int curg = -1;
    int nend = min(n0 + 128, N);
    for (int n = n0 + r; n < nend; n += 2) {
        int g = batch[n];
        if (g != curg) {
            if (curg >= 0) atomicAdd(&pool[(size_t)curg * 128 + d], acc);
            acc = 0.f;
            curg = g;
        }
        acc += out[(size_t)n * 128 + d];
    }
    if (curg >= 0) atomicAdd(&pool[(size_t)curg * 128 + d], acc);
}

__global__ __launch_bounds__(256) void k_count(const int* __restrict__ batch, float* cnt, int N) {
    int i = blockIdx.x * 256 + threadIdx.x;
    if (i < N) atomicAdd(&cnt[batch[i]], 1.0f);
}

__global__ __launch_bounds__(256) void k_pool_div(float* pool, const float* __restrict__ cnt, int G) {
    int gid = blockIdx.x * 256 + threadIdx.x;
    if (gid >= G * 128) return;
    int g = gid >> 7;
    pool[gid] /= fmaxf(cnt[g], 1.0f);
}

// ---------- fallback (ws too small): atomic scatter path ----------
__global__ __launch_bounds__(256) void k_edge_scatter(const int* __restrict__ ei,
                                                      const float* __restrict__ ew,
                                                      const float* __restrict__ dinv,
                                                      const float* __restrict__ h,
                                                      float* out, int E) {
    int gid = blockIdx.x * 256 + threadIdx.x;
    int e = gid >> 5;
    if (e >= E) return;
    int lane = gid & 31;
    int row = ei[e];
    int col = ei[E + e];
    float norm = dinv[row] * dinv[col] * ew[e];
    float4 hv = *(const float4*)&h[(size_t)row * 128 + lane * 4];
    float* o = &out[(size_t)col * 128 + lane * 4];
    atomicAdd(o + 0, hv.x * norm);
    atomicAdd(o + 1, hv.y * norm);
    atomicAdd(o + 2, hv.z * norm);
    atomicAdd(o + 3, hv.w * norm);
}

__global__ __launch_bounds__(256) void k_finalize(float* out, const float* __restrict__ h,
                                                  const float* __restrict__ dinv,
                                                  const float* __restrict__ b,
                                                  const int* __restrict__ batch,
                                                  float* pool, int N) {
    int gid = blockIdx.x * 256 + threadIdx.x;
    if (gid >= N * 128) return;
    int i = gid >> 7;
    int d = gid & 127;
    float di = dinv[i];
    float v = out[gid] + h[gid] * di * di + b[d];
    v = fmaxf(v, 0.f);
    out[gid] = v;
    atomicAdd(&pool[(size_t)batch[i] * 128 + d], v);
}

extern "C" void kernel_launch(void* const* d_in, const int* in_sizes, int n_in,
                              void* d_out, int out_size, void* d_ws, size_t ws_size,
                              hipStream_t stream) {
    const float* x     = (const float*)d_in[0];
    const int*   ei    = (const int*)d_in[1];
    const float* ew    = (const float*)d_in[2];
    const int*   batch = (const int*)d_in[3];
    const float* W     = (const float*)d_in[4];
    const float* b     = (const float*)d_in[5];

    int N = in_sizes[3];        // 50000
    int E = in_sizes[2];        // 800000
    int G = (out_size - N * 128) / 128;   // 500

    float* out  = (float*)d_out;
    float* pool = out + (size_t)N * 128;

    // workspace layout
    float* h      = (float*)d_ws;                    // N*128 f
    int2*  srcval = (int2*)(h + (size_t)N * 128);    // E    int2
    float* deg    = (float*)(srcval + E);            // N    f  (becomes dinv)
    int*   cnti   = (int*)(deg + N);                 // N    i
    int*   rowptr = cnti + N;                        // N+1  i
    int*   fill   = rowptr + N + 1;                  // N    i
    float* cnt    = (float*)(fill + N);              // G    f

    size_t need = (size_t)N * 128 * 4 + (size_t)E * 8 + (size_t)(4 * N + 1) * 4 + (size_t)G * 4;

    hipMemsetAsync(d_out, 0, (size_t)out_size * sizeof(float), stream);

    if (ws_size >= need) {
        hipMemsetAsync(cnti, 0, (size_t)N * sizeof(int), stream);
        hipMemsetAsync(fill, 0, (size_t)N * sizeof(int), stream);
        hipMemsetAsync(cnt, 0, (size_t)G * sizeof(float), stream);

        k_init_deg<<<(N + 255) / 256, 256, 0, stream>>>(deg, N);
        k_deg_count<<<(E + 255) / 256, 256, 0, stream>>>(ei, ew, deg, cnti, E);
        k_dinv<<<(N + 255) / 256, 256, 0, stream>>>(deg, N);
        k_scan<<<1, 1024, 0, stream>>>(cnti, rowptr, N);
        k_fill<<<(E + 255) / 256, 256, 0, stream>>>(ei, ew, deg, rowptr, fill, srcval, E);
        k_gemm<<<(N + 63) / 64, 256, 0, stream>>>(x, W, h, N);
        k_aggregate<<<(N + 3) / 4, 256, 0, stream>>>(srcval, rowptr, h, deg, b, out, N);
        k_count<<<(N + 255) / 256, 256, 0, stream>>>(batch, cnt, N);
        k_pool<<<(N + 127) / 128, 256, 0, stream>>>(out, batch, pool, N);
        k_pool_div<<<(G * 128 + 255) / 256, 256, 0, stream>>>(pool, cnt, G);
    } else {
        // fallback: original atomic path (h, deg, cnt only)
        float* fdeg = h + (size_t)N * 128;
        float* fcnt = fdeg + N;
        hipMemsetAsync(fcnt, 0, (size_t)G * sizeof(float), stream);
        k_init_deg<<<(N + 255) / 256, 256, 0, stream>>>(fdeg, N);
        k_deg_count<<<(E + 255) / 256, 256, 0, stream>>>(ei, ew, fdeg, (int*)fcnt, E); // cnti unused slot
        k_dinv<<<(N + 255) / 256, 256, 0, stream>>>(fdeg, N);
        hipMemsetAsync(fcnt, 0, (size_t)G * sizeof(float), stream);
        k_gemm<<<(N + 63) / 64, 256, 0, stream>>>(x, W, h, N);
        k_edge_scatter<<<((size_t)E * 32 + 255) / 256, 256, 0, stream>>>(ei, ew, fdeg, h, out, E);
        k_count<<<(N + 255) / 256, 256, 0, stream>>>(batch, fcnt, N);
        k_finalize<<<((N * 128) + 255) / 256, 256, 0, stream>>>(out, h, fdeg, b, batch, pool, N);
        k_pool_div<<<(G * 128 + 255) / 256, 256, 0, stream>>>(pool, fcnt, G);
    }
}

// Round 3
// 211.013 us; speedup vs baseline: 7.2423x; 1.7919x over previous
//
#include <hip/hip_runtime.h>

// GCNConv + ReLU + global mean pool for MI355X (gfx950).
// Round 3: single atomic pass (count+pos), atomic-free fill, CSR-gather degree,
// multi-block scan, 2-block/CU GEMM, binary-search pool (no atomics, no memset of out).

// ---------- count + record insertion position (ONE atomic per edge) ----------
__global__ __launch_bounds__(256) void k_count_pos(const int* __restrict__ ei,
                                                   int* cnti, int* __restrict__ pos, int E) {
    int e = blockIdx.x * 256 + threadIdx.x;
    if (e < E) pos[e] = atomicAdd(&cnti[ei[E + e]], 1);
}

// ---------- 3-phase exclusive scan over cnti[0..N) -> rowptr[0..N] ----------
__global__ __launch_bounds__(256) void k_scan1(const int* __restrict__ cnti,
                                               int* __restrict__ rowptr,
                                               int* __restrict__ bsum, int N) {
    __shared__ int wsum[4];
    int t = threadIdx.x;
    int i = blockIdx.x * 256 + t;
    int v = (i < N) ? cnti[i] : 0;
    int lane = t & 63, wid = t >> 6;
    int s = v;
#pragma unroll
    for (int o = 1; o < 64; o <<= 1) {
        int u = __shfl_up(s, o);
        if (lane >= o) s += u;
    }
    if (lane == 63) wsum[wid] = s;
    __syncthreads();
    int off = 0;
#pragma unroll
    for (int w = 0; w < 4; ++w)
        if (w < wid) off += wsum[w];
    if (i < N) rowptr[i] = off + s - v;   // block-local exclusive
    if (t == 255) bsum[blockIdx.x] = off + s;
}

__global__ __launch_bounds__(256) void k_scan2(int* bsum, int nb) {
    __shared__ int wsum[4];
    int t = threadIdx.x;
    int v = (t < nb) ? bsum[t] : 0;
    int lane = t & 63, wid = t >> 6;
    int s = v;
#pragma unroll
    for (int o = 1; o < 64; o <<= 1) {
        int u = __shfl_up(s, o);
        if (lane >= o) s += u;
    }
    if (lane == 63) wsum[wid] = s;
    __syncthreads();
    int off = 0;
#pragma unroll
    for (int w = 0; w < 4; ++w)
        if (w < wid) off += wsum[w];
    if (t < nb) bsum[t] = off + s - v;    // exclusive
    if (t == 255) bsum[nb] = off + s;     // grand total (=E)
}

__global__ __launch_bounds__(256) void k_scan3(int* __restrict__ rowptr,
                                               const int* __restrict__ bsum, int N, int nb) {
    int i = blockIdx.x * 256 + threadIdx.x;
    if (i < N) rowptr[i] += bsum[blockIdx.x];
    if (i == 0) rowptr[N] = bsum[nb];
}

// ---------- atomic-free bucket fill: srcval[slot] = (src row, raw w) ----------
__global__ __launch_bounds__(256) void k_fill(const int* __restrict__ ei,
                                              const float* __restrict__ ew,
                                              const int* __restrict__ rowptr,
                                              const int* __restrict__ pos,
                                              int2* __restrict__ srcval, int E) {
    int e = blockIdx.x * 256 + threadIdx.x;
    if (e >= E) return;
    int row = ei[e];
    int col = ei[E + e];
    srcval[rowptr[col] + pos[e]] = make_int2(row, __float_as_int(ew[e]));
}

// ---------- weighted degree from CSR (coalesced + LDS atomics), dinv=rsqrt ----------
__global__ __launch_bounds__(256) void k_deg_csr(const int* __restrict__ rowptr,
                                                 const int2* __restrict__ srcval,
                                                 float* __restrict__ dinv, int N) {
    __shared__ float sdeg[256];
    __shared__ int srp[257];
    int t = threadIdx.x;
    int n0 = blockIdx.x * 256;
    int nn = min(256, N - n0);
    if (nn <= 0) return;
    sdeg[t] = 1.0f;                       // self-loop weight
    for (int i = t; i <= nn; i += 256) srp[i] = rowptr[n0 + i];
    __syncthreads();
    int beg = srp[0], end = srp[nn];
    for (int j = beg + t; j < end; j += 256) {
        int2 sv = srcval[j];
        int lo = 0, hi = nn - 1;          // find node: srp[lo] <= j < srp[lo+1]
        while (lo < hi) {
            int mid = (lo + hi + 1) >> 1;
            if (srp[mid] <= j) lo = mid; else hi = mid - 1;
        }
        atomicAdd(&sdeg[lo], __int_as_float(sv.y));
    }
    __syncthreads();
    if (t < nn) dinv[n0 + t] = rsqrtf(sdeg[t]);   // deg >= 1 always
}

// ---------- fold dinv[row] into stored weight ----------
__global__ __launch_bounds__(256) void k_scale(int2* __restrict__ srcval,
                                               const float* __restrict__ dinv, int E) {
    int k = blockIdx.x * 256 + threadIdx.x;
    if (k >= E) return;
    int2 sv = srcval[k];
    srcval[k].y = __float_as_int(__int_as_float(sv.y) * dinv[sv.x]);
}

// ---------- h = x @ W, 64 rows x 64 cols per block (66KB LDS -> 2 blocks/CU) ----------
__global__ __launch_bounds__(256) void k_gemm(const float* __restrict__ x,
                                              const float* __restrict__ W,
                                              float* __restrict__ h, int N) {
    __shared__ float sW[128 * 64];
    __shared__ float sX[64 * 132];
    int t = threadIdx.x;
    int rb = blockIdx.x >> 1;
    int c0 = (blockIdx.x & 1) * 64;
    for (int i = t; i < 128 * 16; i += 256) {
        int r = i >> 4, q = i & 15;
        *(float4*)&sW[r * 64 + q * 4] = *(const float4*)&W[r * 128 + c0 + q * 4];
    }
    int row0 = rb * 64;
    int nrows = min(64, N - row0);
    for (int i = t; i < nrows * 32; i += 256) {
        int r = i >> 5, kq = i & 31;
        *(float4*)&sX[r * 132 + kq * 4] = *(const float4*)&x[(size_t)(row0 + r) * 128 + kq * 4];
    }
    __syncthreads();
    int tc = t & 15, trow = t >> 4;
    int d0 = tc * 4;
    float acc[4][4];
#pragma unroll
    for (int r = 0; r < 4; ++r)
#pragma unroll
        for (int d = 0; d < 4; ++d) acc[r][d] = 0.f;

    for (int k = 0; k < 128; k += 4) {
        float4 wv[4];
#pragma unroll
        for (int j = 0; j < 4; ++j) wv[j] = *(float4*)&sW[(k + j) * 64 + d0];
#pragma unroll
        for (int r = 0; r < 4; ++r) {
            float4 xv = *(float4*)&sX[(trow + 16 * r) * 132 + k];
            float xs[4] = {xv.x, xv.y, xv.z, xv.w};
#pragma unroll
            for (int j = 0; j < 4; ++j) {
                const float* wp = (const float*)&wv[j];
#pragma unroll
                for (int d = 0; d < 4; ++d)
                    acc[r][d] = fmaf(xs[j], wp[d], acc[r][d]);
            }
        }
    }
#pragma unroll
    for (int r = 0; r < 4; ++r) {
        int rg = row0 + trow + 16 * r;
        if (rg < N)
            *(float4*)&h[(size_t)rg * 128 + c0 + d0] =
                make_float4(acc[r][0], acc[r][1], acc[r][2], acc[r][3]);
    }
}

// ---------- gather-aggregate: 1 wave/node, 2 dims/lane, 2-deep pipelined ----------
// stored w already includes dinv[row]; final: relu(acc*dinv_i + dinv_i^2*h_i + b)
__global__ __launch_bounds__(256) void k_aggregate(const int2* __restrict__ srcval,
                                                   const int* __restrict__ rowptr,
                                                   const float* __restrict__ h,
                                                   const float* __restrict__ dinv,
                                                   const float* __restrict__ b,
                                                   float* __restrict__ out, int N) {
    int node = blockIdx.x * 4 + (threadIdx.x >> 6);
    if (node >= N) return;
    int lane = threadIdx.x & 63;
    int beg = rowptr[node], end = rowptr[node + 1];
    float2 acc0 = make_float2(0.f, 0.f);
    float2 acc1 = make_float2(0.f, 0.f);
    int j = beg;
    for (; j + 2 <= end; j += 2) {
        int2 a = srcval[j];
        int2 c = srcval[j + 1];
        float2 ha = *(const float2*)&h[(size_t)a.x * 128 + lane * 2];
        float2 hc = *(const float2*)&h[(size_t)c.x * 128 + lane * 2];
        float wa = __int_as_float(a.y), wc = __int_as_float(c.y);
        acc0.x = fmaf(ha.x, wa, acc0.x);
        acc0.y = fmaf(ha.y, wa, acc0.y);
        acc1.x = fmaf(hc.x, wc, acc1.x);
        acc1.y = fmaf(hc.y, wc, acc1.y);
    }
    if (j < end) {
        int2 a = srcval[j];
        float2 ha = *(const float2*)&h[(size_t)a.x * 128 + lane * 2];
        float wa = __int_as_float(a.y);
        acc0.x = fmaf(ha.x, wa, acc0.x);
        acc0.y = fmaf(ha.y, wa, acc0.y);
    }
    acc0.x += acc1.x;
    acc0.y += acc1.y;
    float di = dinv[node];
    float s2 = di * di;
    float2 hs = *(const float2*)&h[(size_t)node * 128 + lane * 2];
    float2 bv = *(const float2*)&b[lane * 2];
    float2 v;
    v.x = fmaxf(fmaf(acc0.x, di, fmaf(hs.x, s2, bv.x)), 0.f);
    v.y = fmaxf(fmaf(acc0.y, di, fmaf(hs.y, s2, bv.y)), 0.f);
    *(float2*)&out[(size_t)node * 128 + lane * 2] = v;
}

// ---------- graph boundaries via binary search (batch is sorted) ----------
__global__ __launch_bounds__(256) void k_gbounds(const int* __restrict__ batch,
                                                 int* __restrict__ gstart, int N, int G) {
    int g = blockIdx.x * 256 + threadIdx.x;
    if (g > G) return;
    int lo = 0, hi = N;
    while (lo < hi) {
        int mid = (lo + hi) >> 1;
        if (batch[mid] < g) lo = mid + 1; else hi = mid;
    }
    gstart[g] = lo;
}

// ---------- pool: one block per graph, no atomics ----------
__global__ __launch_bounds__(256) void k_pool(const float* __restrict__ out,
                                              const int* __restrict__ gstart,
                                              float* __restrict__ pool, int G) {
    __shared__ float sacc[256];
    int g = blockIdx.x;
    int t = threadIdx.x;
    int d = t & 127, r = t >> 7;
    int lo = gstart[g], hi = gstart[g + 1];
    float s = 0.f;
    for (int n = lo + r; n < hi; n += 2)
        s += out[(size_t)n * 128 + d];
    sacc[t] = s;
    __syncthreads();
    if (t < 128) {
        float tot = sacc[t] + sacc[t + 128];
        pool[(size_t)g * 128 + t] = tot / fmaxf((float)(hi - lo), 1.0f);
    }
}

// ---------- fallback kernels (ws too small for pos array) ----------
__global__ __launch_bounds__(256) void k_init_deg(float* deg, int N) {
    int i = blockIdx.x * 256 + threadIdx.x;
    if (i < N) deg[i] = 1.0f;
}

__global__ __launch_bounds__(256) void k_deg_count(const int* __restrict__ ei,
                                                   const float* __restrict__ ew,
                                                   float* deg, int* cnti, int E) {
    int e = blockIdx.x * 256 + threadIdx.x;
    if (e < E) {
        int col = ei[E + e];
        atomicAdd(&deg[col], ew[e]);
        atomicAdd(&cnti[col], 1);
    }
}

__global__ __launch_bounds__(256) void k_dinv(float* deg, int N) {
    int i = blockIdx.x * 256 + threadIdx.x;
    if (i < N) {
        float d = deg[i];
        deg[i] = d > 0.f ? rsqrtf(d) : 0.f;
    }
}

__global__ __launch_bounds__(256) void k_fill_at(const int* __restrict__ ei,
                                                 const float* __restrict__ ew,
                                                 const float* __restrict__ dinv,
                                                 const int* __restrict__ rowptr,
                                                 int* __restrict__ fill,
                                                 int2* __restrict__ srcval, int E) {
    int e = blockIdx.x * 256 + threadIdx.x;
    if (e >= E) return;
    int row = ei[e];
    int col = ei[E + e];
    int p = rowptr[col] + atomicAdd(&fill[col], 1);
    srcval[p] = make_int2(row, __float_as_int(ew[e] * dinv[row]));
}

extern "C" void kernel_launch(void* const* d_in, const int* in_sizes, int n_in,
                              void* d_out, int out_size, void* d_ws, size_t ws_size,
                              hipStream_t stream) {
    const float* x     = (const float*)d_in[0];
    const int*   ei    = (const int*)d_in[1];
    const float* ew    = (const float*)d_in[2];
    const int*   batch = (const int*)d_in[3];
    const float* W     = (const float*)d_in[4];
    const float* b     = (const float*)d_in[5];

    int N = in_sizes[3];                  // 50000
    int E = in_sizes[2];                  // 800000
    int G = (out_size - N * 128) / 128;   // 500

    float* out  = (float*)d_out;
    float* pool = out + (size_t)N * 128;

    int nb = (N + 255) / 256;

    // workspace layout
    float* h      = (float*)d_ws;                       // N*128 f
    int2*  srcval = (int2*)(h + (size_t)N * 128);       // E int2
    float* dinv   = (float*)(srcval + E);               // N f
    int*   cnti   = (int*)(dinv + N);                   // N i
    int*   rowptr = cnti + N;                           // N+1 i
    int*   bsum   = rowptr + N + 1;                     // nb+1 i
    int*   gstart = bsum + nb + 1;                      // G+1 i
    int*   pos    = gstart + G + 1;                     // E i (main) / N i "fill" (fallback)

    size_t base = (size_t)N * 128 * 4 + (size_t)E * 8 +
                  ((size_t)3 * N + 1 + nb + 1 + G + 1) * 4;
    size_t need_main = base + (size_t)E * 4;
    size_t need_fb   = base + (size_t)N * 4;

    if (ws_size >= need_main) {
        hipMemsetAsync(cnti, 0, (size_t)N * sizeof(int), stream);
        k_count_pos<<<(E + 255) / 256, 256, 0, stream>>>(ei, cnti, pos, E);
        k_scan1<<<nb, 256, 0, stream>>>(cnti, rowptr, bsum, N);
        k_scan2<<<1, 256, 0, stream>>>(bsum, nb);
        k_scan3<<<nb, 256, 0, stream>>>(rowptr, bsum, N, nb);
        k_fill<<<(E + 255) / 256, 256, 0, stream>>>(ei, ew, rowptr, pos, srcval, E);
        k_deg_csr<<<nb, 256, 0, stream>>>(rowptr, srcval, dinv, N);
        k_scale<<<(E + 255) / 256, 256, 0, stream>>>(srcval, dinv, E);
        k_gemm<<<((N + 63) / 64) * 2, 256, 0, stream>>>(x, W, h, N);
        k_aggregate<<<(N + 3) / 4, 256, 0, stream>>>(srcval, rowptr, h, dinv, b, out, N);
        k_gbounds<<<(G + 1 + 255) / 256, 256, 0, stream>>>(batch, gstart, N, G);
        k_pool<<<G, 256, 0, stream>>>(out, gstart, pool, G);
    } else if (ws_size >= need_fb) {
        int* fill = pos;   // N ints
        hipMemsetAsync(cnti, 0, (size_t)N * sizeof(int), stream);
        hipMemsetAsync(fill, 0, (size_t)N * sizeof(int), stream);
        k_init_deg<<<nb, 256, 0, stream>>>(dinv, N);
        k_deg_count<<<(E + 255) / 256, 256, 0, stream>>>(ei, ew, dinv, cnti, E);
        k_dinv<<<nb, 256, 0, stream>>>(dinv, N);
        k_scan1<<<nb, 256, 0, stream>>>(cnti, rowptr, bsum, N);
        k_scan2<<<1, 256, 0, stream>>>(bsum, nb);
        k_scan3<<<nb, 256, 0, stream>>>(rowptr, bsum, N, nb);
        k_fill_at<<<(E + 255) / 256, 256, 0, stream>>>(ei, ew, dinv, rowptr, fill, srcval, E);
        k_gemm<<<((N + 63) / 64) * 2, 256, 0, stream>>>(x, W, h, N);
        k_aggregate<<<(N + 3) / 4, 256, 0, stream>>>(srcval, rowptr, h, dinv, b, out, N);
        k_gbounds<<<(G + 1 + 255) / 256, 256, 0, stream>>>(batch, gstart, N, G);
        k_pool<<<G, 256, 0, stream>>>(out, gstart, pool, G);
    }
}

// Round 4
// 187.011 us; speedup vs baseline: 8.1718x; 1.1283x over previous
//
#include <hip/hip_runtime.h>
#include <hip/hip_fp16.h>

// GCNConv + ReLU + global mean pool for MI355X (gfx950).
// Round 4: fp16 h (halves the per-XCD gather traffic floor), 4-way replicated
// count atomics, k_scale folded into aggregate, gbounds folded into pool,
// scan2 folded into scan3. 8 dispatches + 1 memset.

#define REPS 4

// ---------- count + record insertion position (1 atomic/edge, 4-way spread) ----------
__global__ __launch_bounds__(256) void k_count_pos(const int* __restrict__ ei,
                                                   int* cnt4, int* __restrict__ pos,
                                                   int E, int N) {
    int e = blockIdx.x * 256 + threadIdx.x;
    if (e < E) pos[e] = atomicAdd(&cnt4[(e & (REPS - 1)) * N + ei[E + e]], 1);
}

// ---------- scan phase 1 over M=4N counts in view order k=(node*4+rep) ----------
__global__ __launch_bounds__(256) void k_scan1(const int* __restrict__ cnt4,
                                               int* __restrict__ rp4,
                                               int* __restrict__ bsum, int M, int N) {
    __shared__ int wsum[4];
    int t = threadIdx.x;
    int k = blockIdx.x * 256 + t;
    int v = 0;
    if (k < M) v = cnt4[(k & (REPS - 1)) * N + (k >> 2)];
    int lane = t & 63, wid = t >> 6;
    int s = v;
#pragma unroll
    for (int o = 1; o < 64; o <<= 1) {
        int u = __shfl_up(s, o);
        if (lane >= o) s += u;
    }
    if (lane == 63) wsum[wid] = s;
    __syncthreads();
    int off = 0;
#pragma unroll
    for (int w = 0; w < 4; ++w)
        if (w < wid) off += wsum[w];
    if (k < M) rp4[k] = off + s - v;      // block-local exclusive
    if (t == 255) bsum[blockIdx.x] = off + s;
}

// ---------- scan phase 2: each block reduces its own carry, adds ----------
__global__ __launch_bounds__(256) void k_scan3(int* __restrict__ rp4,
                                               const int* __restrict__ bsum,
                                               int M, int E) {
    __shared__ int wsum[4];
    int t = threadIdx.x;
    int bid = blockIdx.x;
    int s = 0;
    for (int j = t; j < bid; j += 256) s += bsum[j];
    int lane = t & 63, wid = t >> 6;
#pragma unroll
    for (int o = 1; o < 64; o <<= 1) s += __shfl_down(s, o);
    if (lane == 0) wsum[wid] = s;
    __syncthreads();
    int off = wsum[0] + wsum[1] + wsum[2] + wsum[3];
    int k = bid * 256 + t;
    if (k < M) rp4[k] += off;
    if (bid == 0 && t == 0) rp4[M] = E;   // grand total known analytically
}

// ---------- atomic-free bucket fill: srcval[slot] = (src row, raw w) ----------
__global__ __launch_bounds__(256) void k_fill(const int* __restrict__ ei,
                                              const float* __restrict__ ew,
                                              const int* __restrict__ rp4,
                                              const int* __restrict__ pos,
                                              int2* __restrict__ srcval, int E) {
    int e = blockIdx.x * 256 + threadIdx.x;
    if (e >= E) return;
    int row = ei[e];
    int col = ei[E + e];
    int slot = rp4[(col << 2) + (e & (REPS - 1))] + pos[e];
    srcval[slot] = make_int2(row, __float_as_int(ew[e]));
}

// ---------- weighted degree from CSR (coalesced + LDS atomics), dinv=rsqrt ----------
__global__ __launch_bounds__(256) void k_deg_csr(const int* __restrict__ rp4,
                                                 const int2* __restrict__ srcval,
                                                 float* __restrict__ dinv, int N) {
    __shared__ float sdeg[256];
    __shared__ int srp[257];
    int t = threadIdx.x;
    int n0 = blockIdx.x * 256;
    int nn = min(256, N - n0);
    if (nn <= 0) return;
    sdeg[t] = 1.0f;                       // self-loop weight
    for (int i = t; i <= nn; i += 256) srp[i] = rp4[(n0 + i) << 2];
    __syncthreads();
    int beg = srp[0], end = srp[nn];
    for (int j = beg + t; j < end; j += 256) {
        int2 sv = srcval[j];
        int lo = 0, hi = nn - 1;          // find node: srp[lo] <= j < srp[lo+1]
        while (lo < hi) {
            int mid = (lo + hi + 1) >> 1;
            if (srp[mid] <= j) lo = mid; else hi = mid - 1;
        }
        atomicAdd(&sdeg[lo], __int_as_float(sv.y));
    }
    __syncthreads();
    if (t < nn) dinv[n0 + t] = rsqrtf(sdeg[t]);   // deg >= 1 always
}

// ---------- h = x @ W -> fp16, 64 rows x 64 cols per block (2 blocks/CU) ----------
__global__ __launch_bounds__(256) void k_gemm(const float* __restrict__ x,
                                              const float* __restrict__ W,
                                              __half* __restrict__ hh, int N) {
    __shared__ float sW[128 * 64];
    __shared__ float sX[64 * 132];
    int t = threadIdx.x;
    int rb = blockIdx.x >> 1;
    int c0 = (blockIdx.x & 1) * 64;
    for (int i = t; i < 128 * 16; i += 256) {
        int r = i >> 4, q = i & 15;
        *(float4*)&sW[r * 64 + q * 4] = *(const float4*)&W[r * 128 + c0 + q * 4];
    }
    int row0 = rb * 64;
    int nrows = min(64, N - row0);
    for (int i = t; i < nrows * 32; i += 256) {
        int r = i >> 5, kq = i & 31;
        *(float4*)&sX[r * 132 + kq * 4] = *(const float4*)&x[(size_t)(row0 + r) * 128 + kq * 4];
    }
    __syncthreads();
    int tc = t & 15, trow = t >> 4;
    int d0 = tc * 4;
    float acc[4][4];
#pragma unroll
    for (int r = 0; r < 4; ++r)
#pragma unroll
        for (int d = 0; d < 4; ++d) acc[r][d] = 0.f;

    for (int k = 0; k < 128; k += 4) {
        float4 wv[4];
#pragma unroll
        for (int j = 0; j < 4; ++j) wv[j] = *(float4*)&sW[(k + j) * 64 + d0];
#pragma unroll
        for (int r = 0; r < 4; ++r) {
            float4 xv = *(float4*)&sX[(trow + 16 * r) * 132 + k];
            float xs[4] = {xv.x, xv.y, xv.z, xv.w};
#pragma unroll
            for (int j = 0; j < 4; ++j) {
                const float* wp = (const float*)&wv[j];
#pragma unroll
                for (int d = 0; d < 4; ++d)
                    acc[r][d] = fmaf(xs[j], wp[d], acc[r][d]);
            }
        }
    }
#pragma unroll
    for (int r = 0; r < 4; ++r) {
        int rg = row0 + trow + 16 * r;
        if (rg < N) {
            union { __half2 h2[2]; uint2 u; } pk;
            pk.h2[0] = __floats2half2_rn(acc[r][0], acc[r][1]);
            pk.h2[1] = __floats2half2_rn(acc[r][2], acc[r][3]);
            *(uint2*)&hh[(size_t)rg * 128 + c0 + d0] = pk.u;
        }
    }
}

// ---------- gather-aggregate: 1 wave/node, 2 dims/lane, fp16 gathers ----------
// out[i] = relu( dinv_i * sum_j w_j*dinv[src_j]*h[src_j] + dinv_i^2*h_i + b )
__global__ __launch_bounds__(256) void k_aggregate(const int2* __restrict__ srcval,
                                                   const int* __restrict__ rp4,
                                                   const __half* __restrict__ hh,
                                                   const float* __restrict__ dinv,
                                                   const float* __restrict__ b,
                                                   float* __restrict__ out, int N) {
    int node = blockIdx.x * 4 + (threadIdx.x >> 6);
    if (node >= N) return;
    int lane = threadIdx.x & 63;
    int beg = rp4[node << 2], end = rp4[(node << 2) + 4];
    float2 acc0 = make_float2(0.f, 0.f);
    float2 acc1 = make_float2(0.f, 0.f);
    int j = beg;
    for (; j + 2 <= end; j += 2) {
        int2 a = srcval[j];
        int2 c = srcval[j + 1];
        float wa = __int_as_float(a.y) * dinv[a.x];
        float wc = __int_as_float(c.y) * dinv[c.x];
        float2 ha = __half22float2(*(const __half2*)&hh[(size_t)a.x * 128 + lane * 2]);
        float2 hc = __half22float2(*(const __half2*)&hh[(size_t)c.x * 128 + lane * 2]);
        acc0.x = fmaf(ha.x, wa, acc0.x);
        acc0.y = fmaf(ha.y, wa, acc0.y);
        acc1.x = fmaf(hc.x, wc, acc1.x);
        acc1.y = fmaf(hc.y, wc, acc1.y);
    }
    if (j < end) {
        int2 a = srcval[j];
        float wa = __int_as_float(a.y) * dinv[a.x];
        float2 ha = __half22float2(*(const __half2*)&hh[(size_t)a.x * 128 + lane * 2]);
        acc0.x = fmaf(ha.x, wa, acc0.x);
        acc0.y = fmaf(ha.y, wa, acc0.y);
    }
    acc0.x += acc1.x;
    acc0.y += acc1.y;
    float di = dinv[node];
    float s2 = di * di;
    float2 hs = __half22float2(*(const __half2*)&hh[(size_t)node * 128 + lane * 2]);
    float2 bv = *(const float2*)&b[lane * 2];
    float2 v;
    v.x = fmaxf(fmaf(acc0.x, di, fmaf(hs.x, s2, bv.x)), 0.f);
    v.y = fmaxf(fmaf(acc0.y, di, fmaf(hs.y, s2, bv.y)), 0.f);
    *(float2*)&out[(size_t)node * 128 + lane * 2] = v;
}

// ---------- pool: one block per graph, bounds by binary search, no atomics ----------
__global__ __launch_bounds__(256) void k_pool(const float* __restrict__ out,
                                              const int* __restrict__ batch,
                                              float* __restrict__ pool, int N, int G) {
    __shared__ float sacc[256];
    __shared__ int bounds[2];
    int g = blockIdx.x;
    int t = threadIdx.x;
    if (t < 2) {
        int target = g + t;               // find first index with batch[idx] >= target
        int lo = 0, hi = N;
        while (lo < hi) {
            int mid = (lo + hi) >> 1;
            if (batch[mid] < target) lo = mid + 1; else hi = mid;
        }
        bounds[t] = lo;
    }
    __syncthreads();
    int lo = bounds[0], hi = bounds[1];
    int d = t & 127, r = t >> 7;
    float s = 0.f;
    for (int n = lo + r; n < hi; n += 2)
        s += out[(size_t)n * 128 + d];
    sacc[t] = s;
    __syncthreads();
    if (t < 128) {
        float tot = sacc[t] + sacc[t + 128];
        pool[(size_t)g * 128 + t] = tot / fmaxf((float)(hi - lo), 1.0f);
    }
}

extern "C" void kernel_launch(void* const* d_in, const int* in_sizes, int n_in,
                              void* d_out, int out_size, void* d_ws, size_t ws_size,
                              hipStream_t stream) {
    const float* x     = (const float*)d_in[0];
    const int*   ei    = (const int*)d_in[1];
    const float* ew    = (const float*)d_in[2];
    const int*   batch = (const int*)d_in[3];
    const float* W     = (const float*)d_in[4];
    const float* b     = (const float*)d_in[5];

    int N = in_sizes[3];                  // 50000
    int E = in_sizes[2];                  // 800000
    int G = (out_size - N * 128) / 128;   // 500
    int M = N * REPS;
    int nb1 = (M + 255) / 256;

    float* out  = (float*)d_out;
    float* pool = out + (size_t)N * 128;

    // workspace layout (~24.3 MB)
    __half* hh     = (__half*)d_ws;                     // N*128 half  (12.8 MB)
    int2*   srcval = (int2*)(hh + (size_t)N * 128);     // E int2      (6.4 MB)
    float*  dinv   = (float*)(srcval + E);              // N f
    int*    cnt4   = (int*)(dinv + N);                  // 4N i
    int*    rp4    = cnt4 + M;                          // 4N+1 i
    int*    bsum   = rp4 + M + 1;                       // nb1 i
    int*    pos    = bsum + nb1;                        // E i         (3.2 MB)

    hipMemsetAsync(cnt4, 0, (size_t)M * sizeof(int), stream);
    k_count_pos<<<(E + 255) / 256, 256, 0, stream>>>(ei, cnt4, pos, E, N);
    k_scan1<<<nb1, 256, 0, stream>>>(cnt4, rp4, bsum, M, N);
    k_scan3<<<nb1, 256, 0, stream>>>(rp4, bsum, M, E);
    k_fill<<<(E + 255) / 256, 256, 0, stream>>>(ei, ew, rp4, pos, srcval, E);
    k_deg_csr<<<(N + 255) / 256, 256, 0, stream>>>(rp4, srcval, dinv, N);
    k_gemm<<<((N + 63) / 64) * 2, 256, 0, stream>>>(x, W, hh, N);
    k_aggregate<<<(N + 3) / 4, 256, 0, stream>>>(srcval, rp4, hh, dinv, b, out, N);
    k_pool<<<G, 256, 0, stream>>>(out, batch, pool, N, G);
}

// Round 5
// 178.267 us; speedup vs baseline: 8.5727x; 1.0490x over previous
//
#include <hip/hip_runtime.h>
#include <hip/hip_fp16.h>

// GCNConv + ReLU + global mean pool for MI355X (gfx950).
// Round 5: h' = dinv*h scaled in GEMM epilogue (kills the dependent dinv[src]
// gather that made round-4 aggregate latency-bound), 4-deep gather unroll,
// 8-way replicated count atomics. Order: CSR build -> deg -> gemm -> aggregate.

#define REPS 8

// ---------- count + record insertion position (1 atomic/edge, 8-way spread) ----------
__global__ __launch_bounds__(256) void k_count_pos(const int* __restrict__ ei,
                                                   int* cnt4, int* __restrict__ pos,
                                                   int E, int N) {
    int e = blockIdx.x * 256 + threadIdx.x;
    if (e < E) pos[e] = atomicAdd(&cnt4[(e & (REPS - 1)) * N + ei[E + e]], 1);
}

// ---------- scan phase 1 over M=8N counts in view order k=(node*8+rep) ----------
__global__ __launch_bounds__(256) void k_scan1(const int* __restrict__ cnt4,
                                               int* __restrict__ rp4,
                                               int* __restrict__ bsum, int M, int N) {
    __shared__ int wsum[4];
    int t = threadIdx.x;
    int k = blockIdx.x * 256 + t;
    int v = 0;
    if (k < M) v = cnt4[(k & (REPS - 1)) * N + (k / REPS)];
    int lane = t & 63, wid = t >> 6;
    int s = v;
#pragma unroll
    for (int o = 1; o < 64; o <<= 1) {
        int u = __shfl_up(s, o);
        if (lane >= o) s += u;
    }
    if (lane == 63) wsum[wid] = s;
    __syncthreads();
    int off = 0;
#pragma unroll
    for (int w = 0; w < 4; ++w)
        if (w < wid) off += wsum[w];
    if (k < M) rp4[k] = off + s - v;      // block-local exclusive
    if (t == 255) bsum[blockIdx.x] = off + s;
}

// ---------- scan phase 2: each block reduces its own carry, adds ----------
__global__ __launch_bounds__(256) void k_scan3(int* __restrict__ rp4,
                                               const int* __restrict__ bsum,
                                               int M, int E) {
    __shared__ int wsum[4];
    int t = threadIdx.x;
    int bid = blockIdx.x;
    int s = 0;
    for (int j = t; j < bid; j += 256) s += bsum[j];
    int lane = t & 63, wid = t >> 6;
#pragma unroll
    for (int o = 1; o < 64; o <<= 1) s += __shfl_down(s, o);
    if (lane == 0) wsum[wid] = s;
    __syncthreads();
    int off = wsum[0] + wsum[1] + wsum[2] + wsum[3];
    int k = bid * 256 + t;
    if (k < M) rp4[k] += off;
    if (bid == 0 && t == 0) rp4[M] = E;   // grand total known analytically
}

// ---------- atomic-free bucket fill: srcval[slot] = (src row, raw w) ----------
__global__ __launch_bounds__(256) void k_fill(const int* __restrict__ ei,
                                              const float* __restrict__ ew,
                                              const int* __restrict__ rp4,
                                              const int* __restrict__ pos,
                                              int2* __restrict__ srcval, int E) {
    int e = blockIdx.x * 256 + threadIdx.x;
    if (e >= E) return;
    int row = ei[e];
    int col = ei[E + e];
    int slot = rp4[col * REPS + (e & (REPS - 1))] + pos[e];
    srcval[slot] = make_int2(row, __float_as_int(ew[e]));
}

// ---------- weighted degree from CSR (coalesced + LDS atomics), dinv=rsqrt ----------
__global__ __launch_bounds__(256) void k_deg_csr(const int* __restrict__ rp4,
                                                 const int2* __restrict__ srcval,
                                                 float* __restrict__ dinv, int N) {
    __shared__ float sdeg[256];
    __shared__ int srp[257];
    int t = threadIdx.x;
    int n0 = blockIdx.x * 256;
    int nn = min(256, N - n0);
    if (nn <= 0) return;
    sdeg[t] = 1.0f;                       // self-loop weight
    for (int i = t; i <= nn; i += 256) srp[i] = rp4[(n0 + i) * REPS];
    __syncthreads();
    int beg = srp[0], end = srp[nn];
    for (int j = beg + t; j < end; j += 256) {
        int2 sv = srcval[j];
        int lo = 0, hi = nn - 1;          // find node: srp[lo] <= j < srp[lo+1]
        while (lo < hi) {
            int mid = (lo + hi + 1) >> 1;
            if (srp[mid] <= j) lo = mid; else hi = mid - 1;
        }
        atomicAdd(&sdeg[lo], __int_as_float(sv.y));
    }
    __syncthreads();
    if (t < nn) dinv[n0 + t] = rsqrtf(sdeg[t]);   // deg >= 1 always
}

// ---------- h' = dinv * (x @ W) -> fp16, 64x64 tile per block ----------
__global__ __launch_bounds__(256) void k_gemm(const float* __restrict__ x,
                                              const float* __restrict__ W,
                                              const float* __restrict__ dinv,
                                              __half* __restrict__ hh, int N) {
    __shared__ float sW[128 * 64];
    __shared__ float sX[64 * 132];
    int t = threadIdx.x;
    int rb = blockIdx.x >> 1;
    int c0 = (blockIdx.x & 1) * 64;
    for (int i = t; i < 128 * 16; i += 256) {
        int r = i >> 4, q = i & 15;
        *(float4*)&sW[r * 64 + q * 4] = *(const float4*)&W[r * 128 + c0 + q * 4];
    }
    int row0 = rb * 64;
    int nrows = min(64, N - row0);
    for (int i = t; i < nrows * 32; i += 256) {
        int r = i >> 5, kq = i & 31;
        *(float4*)&sX[r * 132 + kq * 4] = *(const float4*)&x[(size_t)(row0 + r) * 128 + kq * 4];
    }
    __syncthreads();
    int tc = t & 15, trow = t >> 4;
    int d0 = tc * 4;
    float acc[4][4];
#pragma unroll
    for (int r = 0; r < 4; ++r)
#pragma unroll
        for (int d = 0; d < 4; ++d) acc[r][d] = 0.f;

    for (int k = 0; k < 128; k += 4) {
        float4 wv[4];
#pragma unroll
        for (int j = 0; j < 4; ++j) wv[j] = *(float4*)&sW[(k + j) * 64 + d0];
#pragma unroll
        for (int r = 0; r < 4; ++r) {
            float4 xv = *(float4*)&sX[(trow + 16 * r) * 132 + k];
            float xs[4] = {xv.x, xv.y, xv.z, xv.w};
#pragma unroll
            for (int j = 0; j < 4; ++j) {
                const float* wp = (const float*)&wv[j];
#pragma unroll
                for (int d = 0; d < 4; ++d)
                    acc[r][d] = fmaf(xs[j], wp[d], acc[r][d]);
            }
        }
    }
#pragma unroll
    for (int r = 0; r < 4; ++r) {
        int rg = row0 + trow + 16 * r;
        if (rg < N) {
            float di = dinv[rg];
            union { __half2 h2[2]; uint2 u; } pk;
            pk.h2[0] = __floats2half2_rn(acc[r][0] * di, acc[r][1] * di);
            pk.h2[1] = __floats2half2_rn(acc[r][2] * di, acc[r][3] * di);
            *(uint2*)&hh[(size_t)rg * 128 + c0 + d0] = pk.u;
        }
    }
}

// ---------- gather-aggregate: 1 wave/node, 2 dims/lane, 4-deep pipelined ----------
// out[i] = relu( dinv_i * ( sum_j w_j*h'[src_j] + h'_i ) + b ),  h' = dinv*h
__global__ __launch_bounds__(256) void k_aggregate(const int2* __restrict__ srcval,
                                                   const int* __restrict__ rp4,
                                                   const __half* __restrict__ hh,
                                                   const float* __restrict__ dinv,
                                                   const float* __restrict__ b,
                                                   float* __restrict__ out, int N) {
    int node = blockIdx.x * 4 + (threadIdx.x >> 6);
    if (node >= N) return;
    int lane = threadIdx.x & 63;
    int beg = rp4[node * REPS], end = rp4[(node + 1) * REPS];
    float2 acc0 = make_float2(0.f, 0.f);
    float2 acc1 = make_float2(0.f, 0.f);
    float2 acc2 = make_float2(0.f, 0.f);
    float2 acc3 = make_float2(0.f, 0.f);
    int j = beg;
    for (; j + 4 <= end; j += 4) {
        int2 m0 = srcval[j];
        int2 m1 = srcval[j + 1];
        int2 m2 = srcval[j + 2];
        int2 m3 = srcval[j + 3];
        float2 h0 = __half22float2(*(const __half2*)&hh[(size_t)m0.x * 128 + lane * 2]);
        float2 h1 = __half22float2(*(const __half2*)&hh[(size_t)m1.x * 128 + lane * 2]);
        float2 h2 = __half22float2(*(const __half2*)&hh[(size_t)m2.x * 128 + lane * 2]);
        float2 h3 = __half22float2(*(const __half2*)&hh[(size_t)m3.x * 128 + lane * 2]);
        float w0 = __int_as_float(m0.y), w1 = __int_as_float(m1.y);
        float w2 = __int_as_float(m2.y), w3 = __int_as_float(m3.y);
        acc0.x = fmaf(h0.x, w0, acc0.x); acc0.y = fmaf(h0.y, w0, acc0.y);
        acc1.x = fmaf(h1.x, w1, acc1.x); acc1.y = fmaf(h1.y, w1, acc1.y);
        acc2.x = fmaf(h2.x, w2, acc2.x); acc2.y = fmaf(h2.y, w2, acc2.y);
        acc3.x = fmaf(h3.x, w3, acc3.x); acc3.y = fmaf(h3.y, w3, acc3.y);
    }
    for (; j < end; ++j) {
        int2 m0 = srcval[j];
        float w0 = __int_as_float(m0.y);
        float2 h0 = __half22float2(*(const __half2*)&hh[(size_t)m0.x * 128 + lane * 2]);
        acc0.x = fmaf(h0.x, w0, acc0.x); acc0.y = fmaf(h0.y, w0, acc0.y);
    }
    acc0.x += acc1.x + acc2.x + acc3.x;
    acc0.y += acc1.y + acc2.y + acc3.y;
    float di = dinv[node];
    float2 hs = __half22float2(*(const __half2*)&hh[(size_t)node * 128 + lane * 2]);
    float2 bv = *(const float2*)&b[lane * 2];
    float2 v;
    v.x = fmaxf(fmaf(acc0.x + hs.x, di, bv.x), 0.f);
    v.y = fmaxf(fmaf(acc0.y + hs.y, di, bv.y), 0.f);
    *(float2*)&out[(size_t)node * 128 + lane * 2] = v;
}

// ---------- pool: one block per graph, bounds by binary search, no atomics ----------
__global__ __launch_bounds__(256) void k_pool(const float* __restrict__ out,
                                              const int* __restrict__ batch,
                                              float* __restrict__ pool, int N, int G) {
    __shared__ float sacc[256];
    __shared__ int bounds[2];
    int g = blockIdx.x;
    int t = threadIdx.x;
    if (t < 2) {
        int target = g + t;               // first index with batch[idx] >= target
        int lo = 0, hi = N;
        while (lo < hi) {
            int mid = (lo + hi) >> 1;
            if (batch[mid] < target) lo = mid + 1; else hi = mid;
        }
        bounds[t] = lo;
    }
    __syncthreads();
    int lo = bounds[0], hi = bounds[1];
    int d = t & 127, r = t >> 7;
    float s = 0.f;
    for (int n = lo + r; n < hi; n += 2)
        s += out[(size_t)n * 128 + d];
    sacc[t] = s;
    __syncthreads();
    if (t < 128) {
        float tot = sacc[t] + sacc[t + 128];
        pool[(size_t)g * 128 + t] = tot / fmaxf((float)(hi - lo), 1.0f);
    }
}

extern "C" void kernel_launch(void* const* d_in, const int* in_sizes, int n_in,
                              void* d_out, int out_size, void* d_ws, size_t ws_size,
                              hipStream_t stream) {
    const float* x     = (const float*)d_in[0];
    const int*   ei    = (const int*)d_in[1];
    const float* ew    = (const float*)d_in[2];
    const int*   batch = (const int*)d_in[3];
    const float* W     = (const float*)d_in[4];
    const float* b     = (const float*)d_in[5];

    int N = in_sizes[3];                  // 50000
    int E = in_sizes[2];                  // 800000
    int G = (out_size - N * 128) / 128;   // 500
    int M = N * REPS;
    int nb1 = (M + 255) / 256;

    float* out  = (float*)d_out;
    float* pool = out + (size_t)N * 128;

    // workspace layout (~27 MB)
    __half* hh     = (__half*)d_ws;                     // N*128 half  (12.8 MB)
    int2*   srcval = (int2*)(hh + (size_t)N * 128);     // E int2      (6.4 MB)
    float*  dinv   = (float*)(srcval + E);              // N f
    int*    cnt4   = (int*)(dinv + N);                  // 8N i        (1.6 MB)
    int*    rp4    = cnt4 + M;                          // 8N+1 i      (1.6 MB)
    int*    bsum   = rp4 + M + 1;                       // nb1 i
    int*    pos    = bsum + nb1;                        // E i         (3.2 MB)

    hipMemsetAsync(cnt4, 0, (size_t)M * sizeof(int), stream);
    k_count_pos<<<(E + 255) / 256, 256, 0, stream>>>(ei, cnt4, pos, E, N);
    k_scan1<<<nb1, 256, 0, stream>>>(cnt4, rp4, bsum, M, N);
    k_scan3<<<nb1, 256, 0, stream>>>(rp4, bsum, M, E);
    k_fill<<<(E + 255) / 256, 256, 0, stream>>>(ei, ew, rp4, pos, srcval, E);
    k_deg_csr<<<(N + 255) / 256, 256, 0, stream>>>(rp4, srcval, dinv, N);
    k_gemm<<<((N + 63) / 64) * 2, 256, 0, stream>>>(x, W, dinv, hh, N);
    k_aggregate<<<(N + 3) / 4, 256, 0, stream>>>(srcval, rp4, hh, dinv, b, out, N);
    k_pool<<<G, 256, 0, stream>>>(out, batch, pool, N, G);
}

// Round 6
// 158.551 us; speedup vs baseline: 9.6387x; 1.1243x over previous
//
#include <hip/hip_runtime.h>
#include <hip/hip_fp16.h>

// GCNConv + ReLU + global mean pool for MI355X (gfx950).
// Round 6: MFMA fp16 GEMM (v_mfma_f32_16x16x32_f16), W pre-transposed to Wt[n][k]
// fp16 so both fragments are contiguous-K ds_read_b128. K-permutation is chosen
// (k = (lane>>4)*8+e) identically for A and B fragments -> correct for any HW
// internal K order. CSR/aggregate/pool pipeline unchanged from round 5.

#define REPS 8

typedef _Float16 f16;
typedef _Float16 half8 __attribute__((ext_vector_type(8)));
typedef float f32x4 __attribute__((ext_vector_type(4)));

// ---------- count + record insertion position (1 atomic/edge, 8-way spread) ----------
__global__ __launch_bounds__(256) void k_count_pos(const int* __restrict__ ei,
                                                   int* cnt4, int* __restrict__ pos,
                                                   int E, int N) {
    int e = blockIdx.x * 256 + threadIdx.x;
    if (e < E) pos[e] = atomicAdd(&cnt4[(e & (REPS - 1)) * N + ei[E + e]], 1);
}

// ---------- scan phase 1 over M=8N counts in view order k=(node*8+rep) ----------
__global__ __launch_bounds__(256) void k_scan1(const int* __restrict__ cnt4,
                                               int* __restrict__ rp4,
                                               int* __restrict__ bsum, int M, int N) {
    __shared__ int wsum[4];
    int t = threadIdx.x;
    int k = blockIdx.x * 256 + t;
    int v = 0;
    if (k < M) v = cnt4[(k & (REPS - 1)) * N + (k / REPS)];
    int lane = t & 63, wid = t >> 6;
    int s = v;
#pragma unroll
    for (int o = 1; o < 64; o <<= 1) {
        int u = __shfl_up(s, o);
        if (lane >= o) s += u;
    }
    if (lane == 63) wsum[wid] = s;
    __syncthreads();
    int off = 0;
#pragma unroll
    for (int w = 0; w < 4; ++w)
        if (w < wid) off += wsum[w];
    if (k < M) rp4[k] = off + s - v;      // block-local exclusive
    if (t == 255) bsum[blockIdx.x] = off + s;
}

// ---------- scan phase 2: each block reduces its own carry, adds ----------
__global__ __launch_bounds__(256) void k_scan3(int* __restrict__ rp4,
                                               const int* __restrict__ bsum,
                                               int M, int E) {
    __shared__ int wsum[4];
    int t = threadIdx.x;
    int bid = blockIdx.x;
    int s = 0;
    for (int j = t; j < bid; j += 256) s += bsum[j];
    int lane = t & 63, wid = t >> 6;
#pragma unroll
    for (int o = 1; o < 64; o <<= 1) s += __shfl_down(s, o);
    if (lane == 0) wsum[wid] = s;
    __syncthreads();
    int off = wsum[0] + wsum[1] + wsum[2] + wsum[3];
    int k = bid * 256 + t;
    if (k < M) rp4[k] += off;
    if (bid == 0 && t == 0) rp4[M] = E;   // grand total known analytically
}

// ---------- atomic-free bucket fill: srcval[slot] = (src row, raw w) ----------
__global__ __launch_bounds__(256) void k_fill(const int* __restrict__ ei,
                                              const float* __restrict__ ew,
                                              const int* __restrict__ rp4,
                                              const int* __restrict__ pos,
                                              int2* __restrict__ srcval, int E) {
    int e = blockIdx.x * 256 + threadIdx.x;
    if (e >= E) return;
    int row = ei[e];
    int col = ei[E + e];
    int slot = rp4[col * REPS + (e & (REPS - 1))] + pos[e];
    srcval[slot] = make_int2(row, __float_as_int(ew[e]));
}

// ---------- weighted degree from CSR (coalesced + LDS atomics), dinv=rsqrt ----------
__global__ __launch_bounds__(256) void k_deg_csr(const int* __restrict__ rp4,
                                                 const int2* __restrict__ srcval,
                                                 float* __restrict__ dinv, int N) {
    __shared__ float sdeg[256];
    __shared__ int srp[257];
    int t = threadIdx.x;
    int n0 = blockIdx.x * 256;
    int nn = min(256, N - n0);
    if (nn <= 0) return;
    sdeg[t] = 1.0f;                       // self-loop weight
    for (int i = t; i <= nn; i += 256) srp[i] = rp4[(n0 + i) * REPS];
    __syncthreads();
    int beg = srp[0], end = srp[nn];
    for (int j = beg + t; j < end; j += 256) {
        int2 sv = srcval[j];
        int lo = 0, hi = nn - 1;          // find node: srp[lo] <= j < srp[lo+1]
        while (lo < hi) {
            int mid = (lo + hi + 1) >> 1;
            if (srp[mid] <= j) lo = mid; else hi = mid - 1;
        }
        atomicAdd(&sdeg[lo], __int_as_float(sv.y));
    }
    __syncthreads();
    if (t < nn) dinv[n0 + t] = rsqrtf(sdeg[t]);   // deg >= 1 always
}

// ---------- W (f32 [k][n]) -> Wt (f16 [n][k]) ----------
__global__ __launch_bounds__(256) void k_wt(const float* __restrict__ W,
                                            f16* __restrict__ Wt) {
    int t = threadIdx.x;
    int n = blockIdx.x * 8 + (t >> 5);
    int k = (t & 31) * 4;
    union { f16 h[4]; uint2 u; } p;
#pragma unroll
    for (int j = 0; j < 4; ++j) p.h[j] = (f16)W[(k + j) * 128 + n];
    *(uint2*)&Wt[n * 128 + k] = p.u;
}

// ---------- h' = dinv * (x @ W) -> fp16 via MFMA, 128x128 tile per block ----------
__global__ __launch_bounds__(256) void k_gemm(const float* __restrict__ x,
                                              const f16* __restrict__ Wt,
                                              const float* __restrict__ dinv,
                                              f16* __restrict__ hh, int N) {
    __shared__ f16 sX[128 * 136];   // pad 8 halves: 2-way (free) bank conflicts
    __shared__ f16 sW[128 * 136];
    int t = threadIdx.x;
    int row0 = blockIdx.x * 128;
    // stage Wt (f16, contiguous b128 copies)
#pragma unroll
    for (int it = 0; it < 8; ++it) {
        int i = t + 256 * it;             // 2048 chunks of 8 halves
        int n = i >> 4, k8 = (i & 15) * 8;
        *(half8*)&sW[n * 136 + k8] = *(const half8*)&Wt[n * 128 + k8];
    }
    // stage x tile (f32 -> f16)
#pragma unroll
    for (int it = 0; it < 16; ++it) {
        int i = t + 256 * it;             // 4096 float4s
        int r = i >> 5, c4 = (i & 31) * 4;
        float4 xv = make_float4(0.f, 0.f, 0.f, 0.f);
        if (row0 + r < N) xv = *(const float4*)&x[(size_t)(row0 + r) * 128 + c4];
        union { f16 h[4]; uint2 u; } p;
        p.h[0] = (f16)xv.x; p.h[1] = (f16)xv.y; p.h[2] = (f16)xv.z; p.h[3] = (f16)xv.w;
        *(uint2*)&sX[r * 136 + c4] = p.u;
    }
    __syncthreads();

    int w = t >> 6, l = t & 63;
    int lm = l & 15, lg = l >> 4;
    f32x4 acc[2][8];
#pragma unroll
    for (int rt = 0; rt < 2; ++rt)
#pragma unroll
        for (int ct = 0; ct < 8; ++ct) acc[rt][ct] = (f32x4){0.f, 0.f, 0.f, 0.f};

    int arow = w * 32 + lm;
#pragma unroll
    for (int ks = 0; ks < 4; ++ks) {
        int ko = ks * 32 + lg * 8;        // our K-bijection, same for A and B
        half8 a0 = *(const half8*)&sX[arow * 136 + ko];
        half8 a1 = *(const half8*)&sX[(arow + 16) * 136 + ko];
#pragma unroll
        for (int ct = 0; ct < 8; ++ct) {
            half8 bf = *(const half8*)&sW[(ct * 16 + lm) * 136 + ko];
            acc[0][ct] = __builtin_amdgcn_mfma_f32_16x16x32_f16(a0, bf, acc[0][ct], 0, 0, 0);
            acc[1][ct] = __builtin_amdgcn_mfma_f32_16x16x32_f16(a1, bf, acc[1][ct], 0, 0, 0);
        }
    }

    // epilogue: scale by dinv, repack through this wave's own sX rows (no barrier:
    // each wave reads/writes only rows [w*32, w*32+32) )
#pragma unroll
    for (int rt = 0; rt < 2; ++rt) {
#pragma unroll
        for (int r = 0; r < 4; ++r) {
            int lrow = w * 32 + rt * 16 + lg * 4 + r;   // D row = (lane>>4)*4 + reg
            int grow = row0 + lrow;
            float di = (grow < N) ? dinv[grow] : 0.f;
#pragma unroll
            for (int ct = 0; ct < 8; ++ct)
                sX[lrow * 136 + ct * 16 + lm] = (f16)(acc[rt][ct][r] * di);  // D col = lane&15
        }
    }
#pragma unroll
    for (int it = 0; it < 8; ++it) {
        int i = l + 64 * it;              // 32 rows x 16 chunks per wave
        int lr = i >> 4, k8 = (i & 15) * 8;
        int grow = row0 + w * 32 + lr;
        if (grow < N)
            *(half8*)&hh[(size_t)grow * 128 + k8] =
                *(const half8*)&sX[(w * 32 + lr) * 136 + k8];
    }
}

// ---------- gather-aggregate: 1 wave/node, 2 dims/lane, 4-deep pipelined ----------
// out[i] = relu( dinv_i * ( sum_j w_j*h'[src_j] + h'_i ) + b ),  h' = dinv*h
__global__ __launch_bounds__(256) void k_aggregate(const int2* __restrict__ srcval,
                                                   const int* __restrict__ rp4,
                                                   const __half* __restrict__ hh,
                                                   const float* __restrict__ dinv,
                                                   const float* __restrict__ b,
                                                   float* __restrict__ out, int N) {
    int node = blockIdx.x * 4 + (threadIdx.x >> 6);
    if (node >= N) return;
    int lane = threadIdx.x & 63;
    int beg = rp4[node * REPS], end = rp4[(node + 1) * REPS];
    float2 acc0 = make_float2(0.f, 0.f);
    float2 acc1 = make_float2(0.f, 0.f);
    float2 acc2 = make_float2(0.f, 0.f);
    float2 acc3 = make_float2(0.f, 0.f);
    int j = beg;
    for (; j + 4 <= end; j += 4) {
        int2 m0 = srcval[j];
        int2 m1 = srcval[j + 1];
        int2 m2 = srcval[j + 2];
        int2 m3 = srcval[j + 3];
        float2 h0 = __half22float2(*(const __half2*)&hh[(size_t)m0.x * 128 + lane * 2]);
        float2 h1 = __half22float2(*(const __half2*)&hh[(size_t)m1.x * 128 + lane * 2]);
        float2 h2 = __half22float2(*(const __half2*)&hh[(size_t)m2.x * 128 + lane * 2]);
        float2 h3 = __half22float2(*(const __half2*)&hh[(size_t)m3.x * 128 + lane * 2]);
        float w0 = __int_as_float(m0.y), w1 = __int_as_float(m1.y);
        float w2 = __int_as_float(m2.y), w3 = __int_as_float(m3.y);
        acc0.x = fmaf(h0.x, w0, acc0.x); acc0.y = fmaf(h0.y, w0, acc0.y);
        acc1.x = fmaf(h1.x, w1, acc1.x); acc1.y = fmaf(h1.y, w1, acc1.y);
        acc2.x = fmaf(h2.x, w2, acc2.x); acc2.y = fmaf(h2.y, w2, acc2.y);
        acc3.x = fmaf(h3.x, w3, acc3.x); acc3.y = fmaf(h3.y, w3, acc3.y);
    }
    for (; j < end; ++j) {
        int2 m0 = srcval[j];
        float w0 = __int_as_float(m0.y);
        float2 h0 = __half22float2(*(const __half2*)&hh[(size_t)m0.x * 128 + lane * 2]);
        acc0.x = fmaf(h0.x, w0, acc0.x); acc0.y = fmaf(h0.y, w0, acc0.y);
    }
    acc0.x += acc1.x + acc2.x + acc3.x;
    acc0.y += acc1.y + acc2.y + acc3.y;
    float di = dinv[node];
    float2 hs = __half22float2(*(const __half2*)&hh[(size_t)node * 128 + lane * 2]);
    float2 bv = *(const float2*)&b[lane * 2];
    float2 v;
    v.x = fmaxf(fmaf(acc0.x + hs.x, di, bv.x), 0.f);
    v.y = fmaxf(fmaf(acc0.y + hs.y, di, bv.y), 0.f);
    *(float2*)&out[(size_t)node * 128 + lane * 2] = v;
}

// ---------- pool: one block per graph, bounds by binary search, no atomics ----------
__global__ __launch_bounds__(256) void k_pool(const float* __restrict__ out,
                                              const int* __restrict__ batch,
                                              float* __restrict__ pool, int N, int G) {
    __shared__ float sacc[256];
    __shared__ int bounds[2];
    int g = blockIdx.x;
    int t = threadIdx.x;
    if (t < 2) {
        int target = g + t;               // first index with batch[idx] >= target
        int lo = 0, hi = N;
        while (lo < hi) {
            int mid = (lo + hi) >> 1;
            if (batch[mid] < target) lo = mid + 1; else hi = mid;
        }
        bounds[t] = lo;
    }
    __syncthreads();
    int lo = bounds[0], hi = bounds[1];
    int d = t & 127, r = t >> 7;
    float s = 0.f;
    for (int n = lo + r; n < hi; n += 2)
        s += out[(size_t)n * 128 + d];
    sacc[t] = s;
    __syncthreads();
    if (t < 128) {
        float tot = sacc[t] + sacc[t + 128];
        pool[(size_t)g * 128 + t] = tot / fmaxf((float)(hi - lo), 1.0f);
    }
}

extern "C" void kernel_launch(void* const* d_in, const int* in_sizes, int n_in,
                              void* d_out, int out_size, void* d_ws, size_t ws_size,
                              hipStream_t stream) {
    const float* x     = (const float*)d_in[0];
    const int*   ei    = (const int*)d_in[1];
    const float* ew    = (const float*)d_in[2];
    const int*   batch = (const int*)d_in[3];
    const float* W     = (const float*)d_in[4];
    const float* b     = (const float*)d_in[5];

    int N = in_sizes[3];                  // 50000
    int E = in_sizes[2];                  // 800000
    int G = (out_size - N * 128) / 128;   // 500
    int M = N * REPS;
    int nb1 = (M + 255) / 256;

    float* out  = (float*)d_out;
    float* pool = out + (size_t)N * 128;

    // workspace layout (~26 MB)
    f16*    hh     = (f16*)d_ws;                        // N*128 f16   (12.8 MB)
    int2*   srcval = (int2*)(hh + (size_t)N * 128);     // E int2      (6.4 MB)
    float*  dinv   = (float*)(srcval + E);              // N f
    int*    cnt4   = (int*)(dinv + N);                  // 8N i        (1.6 MB)
    int*    rp4    = cnt4 + M;                          // 8N+1 i      (1.6 MB)
    int*    bsum   = rp4 + M + 1;                       // nb1 i
    int*    pos    = bsum + nb1;                        // E i         (3.2 MB)
    f16*    Wt     = (f16*)(pos + E);                   // 128*128 f16 (32 KB)

    hipMemsetAsync(cnt4, 0, (size_t)M * sizeof(int), stream);
    k_wt<<<16, 256, 0, stream>>>(W, Wt);
    k_count_pos<<<(E + 255) / 256, 256, 0, stream>>>(ei, cnt4, pos, E, N);
    k_scan1<<<nb1, 256, 0, stream>>>(cnt4, rp4, bsum, M, N);
    k_scan3<<<nb1, 256, 0, stream>>>(rp4, bsum, M, E);
    k_fill<<<(E + 255) / 256, 256, 0, stream>>>(ei, ew, rp4, pos, srcval, E);
    k_deg_csr<<<(N + 255) / 256, 256, 0, stream>>>(rp4, srcval, dinv, N);
    k_gemm<<<(N + 127) / 128, 256, 0, stream>>>(x, Wt, dinv, hh, N);
    k_aggregate<<<(N + 3) / 4, 256, 0, stream>>>(srcval, rp4, (const __half*)hh, dinv, b, out, N);
    k_pool<<<G, 256, 0, stream>>>(out, batch, pool, N, G);
}

// Round 7
// 151.328 us; speedup vs baseline: 10.0987x; 1.0477x over previous
//
#include <hip/hip_runtime.h>
#include <hip/hip_fp16.h>

// GCNConv + ReLU + global mean pool for MI355X (gfx950).
// Round 7: custom zero+Wt init kernel (rocclr fillBuffer was 42us for 1.6MB),
// 8-deep gather unroll in aggregate. Pipeline otherwise unchanged from round 6.

#define REPS 8

typedef _Float16 f16;
typedef _Float16 half8 __attribute__((ext_vector_type(8)));
typedef float f32x4 __attribute__((ext_vector_type(4)));

// ---------- fused init: zero cnt4 (int4 stores) + W -> Wt (f16 [n][k]) ----------
__global__ __launch_bounds__(256) void k_init(int* __restrict__ cnt4, int M4, int nzb,
                                              const float* __restrict__ W,
                                              f16* __restrict__ Wt) {
    int bid = blockIdx.x;
    int t = threadIdx.x;
    if (bid < nzb) {
        int i = bid * 256 + t;
        if (i < M4) ((int4*)cnt4)[i] = make_int4(0, 0, 0, 0);
    } else {
        int n = (bid - nzb) * 8 + (t >> 5);
        int k = (t & 31) * 4;
        union { f16 h[4]; uint2 u; } p;
#pragma unroll
        for (int j = 0; j < 4; ++j) p.h[j] = (f16)W[(k + j) * 128 + n];
        *(uint2*)&Wt[n * 128 + k] = p.u;
    }
}

// ---------- count + record insertion position (1 atomic/edge, 8-way spread) ----------
__global__ __launch_bounds__(256) void k_count_pos(const int* __restrict__ ei,
                                                   int* cnt4, int* __restrict__ pos,
                                                   int E, int N) {
    int e = blockIdx.x * 256 + threadIdx.x;
    if (e < E) pos[e] = atomicAdd(&cnt4[(e & (REPS - 1)) * N + ei[E + e]], 1);
}

// ---------- scan phase 1 over M=8N counts in view order k=(node*8+rep) ----------
__global__ __launch_bounds__(256) void k_scan1(const int* __restrict__ cnt4,
                                               int* __restrict__ rp4,
                                               int* __restrict__ bsum, int M, int N) {
    __shared__ int wsum[4];
    int t = threadIdx.x;
    int k = blockIdx.x * 256 + t;
    int v = 0;
    if (k < M) v = cnt4[(k & (REPS - 1)) * N + (k / REPS)];
    int lane = t & 63, wid = t >> 6;
    int s = v;
#pragma unroll
    for (int o = 1; o < 64; o <<= 1) {
        int u = __shfl_up(s, o);
        if (lane >= o) s += u;
    }
    if (lane == 63) wsum[wid] = s;
    __syncthreads();
    int off = 0;
#pragma unroll
    for (int w = 0; w < 4; ++w)
        if (w < wid) off += wsum[w];
    if (k < M) rp4[k] = off + s - v;      // block-local exclusive
    if (t == 255) bsum[blockIdx.x] = off + s;
}

// ---------- scan phase 2: each block reduces its own carry, adds ----------
__global__ __launch_bounds__(256) void k_scan3(int* __restrict__ rp4,
                                               const int* __restrict__ bsum,
                                               int M, int E) {
    __shared__ int wsum[4];
    int t = threadIdx.x;
    int bid = blockIdx.x;
    int s = 0;
    for (int j = t; j < bid; j += 256) s += bsum[j];
    int lane = t & 63, wid = t >> 6;
#pragma unroll
    for (int o = 1; o < 64; o <<= 1) s += __shfl_down(s, o);
    if (lane == 0) wsum[wid] = s;
    __syncthreads();
    int off = wsum[0] + wsum[1] + wsum[2] + wsum[3];
    int k = bid * 256 + t;
    if (k < M) rp4[k] += off;
    if (bid == 0 && t == 0) rp4[M] = E;   // grand total known analytically
}

// ---------- atomic-free bucket fill: srcval[slot] = (src row, raw w) ----------
__global__ __launch_bounds__(256) void k_fill(const int* __restrict__ ei,
                                              const float* __restrict__ ew,
                                              const int* __restrict__ rp4,
                                              const int* __restrict__ pos,
                                              int2* __restrict__ srcval, int E) {
    int e = blockIdx.x * 256 + threadIdx.x;
    if (e >= E) return;
    int row = ei[e];
    int col = ei[E + e];
    int slot = rp4[col * REPS + (e & (REPS - 1))] + pos[e];
    srcval[slot] = make_int2(row, __float_as_int(ew[e]));
}

// ---------- weighted degree from CSR (coalesced + LDS atomics), dinv=rsqrt ----------
__global__ __launch_bounds__(256) void k_deg_csr(const int* __restrict__ rp4,
                                                 const int2* __restrict__ srcval,
                                                 float* __restrict__ dinv, int N) {
    __shared__ float sdeg[256];
    __shared__ int srp[257];
    int t = threadIdx.x;
    int n0 = blockIdx.x * 256;
    int nn = min(256, N - n0);
    if (nn <= 0) return;
    sdeg[t] = 1.0f;                       // self-loop weight
    for (int i = t; i <= nn; i += 256) srp[i] = rp4[(n0 + i) * REPS];
    __syncthreads();
    int beg = srp[0], end = srp[nn];
    for (int j = beg + t; j < end; j += 256) {
        int2 sv = srcval[j];
        int lo = 0, hi = nn - 1;          // find node: srp[lo] <= j < srp[lo+1]
        while (lo < hi) {
            int mid = (lo + hi + 1) >> 1;
            if (srp[mid] <= j) lo = mid; else hi = mid - 1;
        }
        atomicAdd(&sdeg[lo], __int_as_float(sv.y));
    }
    __syncthreads();
    if (t < nn) dinv[n0 + t] = rsqrtf(sdeg[t]);   // deg >= 1 always
}

// ---------- h' = dinv * (x @ W) -> fp16 via MFMA, 128x128 tile per block ----------
__global__ __launch_bounds__(256) void k_gemm(const float* __restrict__ x,
                                              const f16* __restrict__ Wt,
                                              const float* __restrict__ dinv,
                                              f16* __restrict__ hh, int N) {
    __shared__ f16 sX[128 * 136];   // pad 8 halves: 2-way (free) bank conflicts
    __shared__ f16 sW[128 * 136];
    int t = threadIdx.x;
    int row0 = blockIdx.x * 128;
    // stage Wt (f16, contiguous b128 copies)
#pragma unroll
    for (int it = 0; it < 8; ++it) {
        int i = t + 256 * it;             // 2048 chunks of 8 halves
        int n = i >> 4, k8 = (i & 15) * 8;
        *(half8*)&sW[n * 136 + k8] = *(const half8*)&Wt[n * 128 + k8];
    }
    // stage x tile (f32 -> f16)
#pragma unroll
    for (int it = 0; it < 16; ++it) {
        int i = t + 256 * it;             // 4096 float4s
        int r = i >> 5, c4 = (i & 31) * 4;
        float4 xv = make_float4(0.f, 0.f, 0.f, 0.f);
        if (row0 + r < N) xv = *(const float4*)&x[(size_t)(row0 + r) * 128 + c4];
        union { f16 h[4]; uint2 u; } p;
        p.h[0] = (f16)xv.x; p.h[1] = (f16)xv.y; p.h[2] = (f16)xv.z; p.h[3] = (f16)xv.w;
        *(uint2*)&sX[r * 136 + c4] = p.u;
    }
    __syncthreads();

    int w = t >> 6, l = t & 63;
    int lm = l & 15, lg = l >> 4;
    f32x4 acc[2][8];
#pragma unroll
    for (int rt = 0; rt < 2; ++rt)
#pragma unroll
        for (int ct = 0; ct < 8; ++ct) acc[rt][ct] = (f32x4){0.f, 0.f, 0.f, 0.f};

    int arow = w * 32 + lm;
#pragma unroll
    for (int ks = 0; ks < 4; ++ks) {
        int ko = ks * 32 + lg * 8;        // our K-bijection, same for A and B
        half8 a0 = *(const half8*)&sX[arow * 136 + ko];
        half8 a1 = *(const half8*)&sX[(arow + 16) * 136 + ko];
#pragma unroll
        for (int ct = 0; ct < 8; ++ct) {
            half8 bf = *(const half8*)&sW[(ct * 16 + lm) * 136 + ko];
            acc[0][ct] = __builtin_amdgcn_mfma_f32_16x16x32_f16(a0, bf, acc[0][ct], 0, 0, 0);
            acc[1][ct] = __builtin_amdgcn_mfma_f32_16x16x32_f16(a1, bf, acc[1][ct], 0, 0, 0);
        }
    }

    // epilogue: scale by dinv, repack through this wave's own sX rows (no barrier:
    // each wave reads/writes only rows [w*32, w*32+32) )
#pragma unroll
    for (int rt = 0; rt < 2; ++rt) {
#pragma unroll
        for (int r = 0; r < 4; ++r) {
            int lrow = w * 32 + rt * 16 + lg * 4 + r;   // D row = (lane>>4)*4 + reg
            int grow = row0 + lrow;
            float di = (grow < N) ? dinv[grow] : 0.f;
#pragma unroll
            for (int ct = 0; ct < 8; ++ct)
                sX[lrow * 136 + ct * 16 + lm] = (f16)(acc[rt][ct][r] * di);  // D col = lane&15
        }
    }
#pragma unroll
    for (int it = 0; it < 8; ++it) {
        int i = l + 64 * it;              // 32 rows x 16 chunks per wave
        int lr = i >> 4, k8 = (i & 15) * 8;
        int grow = row0 + w * 32 + lr;
        if (grow < N)
            *(half8*)&hh[(size_t)grow * 128 + k8] =
                *(const half8*)&sX[(w * 32 + lr) * 136 + k8];
    }
}

// ---------- gather-aggregate: 1 wave/node, 2 dims/lane, 8-deep pipelined ----------
// out[i] = relu( dinv_i * ( sum_j w_j*h'[src_j] + h'_i ) + b ),  h' = dinv*h
__global__ __launch_bounds__(256) void k_aggregate(const int2* __restrict__ srcval,
                                                   const int* __restrict__ rp4,
                                                   const __half* __restrict__ hh,
                                                   const float* __restrict__ dinv,
                                                   const float* __restrict__ b,
                                                   float* __restrict__ out, int N) {
    int node = blockIdx.x * 4 + (threadIdx.x >> 6);
    if (node >= N) return;
    int lane = threadIdx.x & 63;
    int beg = rp4[node * REPS], end = rp4[(node + 1) * REPS];
    float2 acc0 = make_float2(0.f, 0.f);
    float2 acc1 = make_float2(0.f, 0.f);
    float2 acc2 = make_float2(0.f, 0.f);
    float2 acc3 = make_float2(0.f, 0.f);
    int j = beg;
    for (; j + 8 <= end; j += 8) {
        int2 m[8];
#pragma unroll
        for (int q = 0; q < 8; ++q) m[q] = srcval[j + q];
        float2 hv[8];
#pragma unroll
        for (int q = 0; q < 8; ++q)
            hv[q] = __half22float2(*(const __half2*)&hh[(size_t)m[q].x * 128 + lane * 2]);
#pragma unroll
        for (int q = 0; q < 8; ++q) {
            float wq = __int_as_float(m[q].y);
            if ((q & 3) == 0) { acc0.x = fmaf(hv[q].x, wq, acc0.x); acc0.y = fmaf(hv[q].y, wq, acc0.y); }
            if ((q & 3) == 1) { acc1.x = fmaf(hv[q].x, wq, acc1.x); acc1.y = fmaf(hv[q].y, wq, acc1.y); }
            if ((q & 3) == 2) { acc2.x = fmaf(hv[q].x, wq, acc2.x); acc2.y = fmaf(hv[q].y, wq, acc2.y); }
            if ((q & 3) == 3) { acc3.x = fmaf(hv[q].x, wq, acc3.x); acc3.y = fmaf(hv[q].y, wq, acc3.y); }
        }
    }
    for (; j + 2 <= end; j += 2) {
        int2 m0 = srcval[j];
        int2 m1 = srcval[j + 1];
        float2 h0 = __half22float2(*(const __half2*)&hh[(size_t)m0.x * 128 + lane * 2]);
        float2 h1 = __half22float2(*(const __half2*)&hh[(size_t)m1.x * 128 + lane * 2]);
        float w0 = __int_as_float(m0.y), w1 = __int_as_float(m1.y);
        acc0.x = fmaf(h0.x, w0, acc0.x); acc0.y = fmaf(h0.y, w0, acc0.y);
        acc1.x = fmaf(h1.x, w1, acc1.x); acc1.y = fmaf(h1.y, w1, acc1.y);
    }
    if (j < end) {
        int2 m0 = srcval[j];
        float w0 = __int_as_float(m0.y);
        float2 h0 = __half22float2(*(const __half2*)&hh[(size_t)m0.x * 128 + lane * 2]);
        acc0.x = fmaf(h0.x, w0, acc0.x); acc0.y = fmaf(h0.y, w0, acc0.y);
    }
    acc0.x += acc1.x + acc2.x + acc3.x;
    acc0.y += acc1.y + acc2.y + acc3.y;
    float di = dinv[node];
    float2 hs = __half22float2(*(const __half2*)&hh[(size_t)node * 128 + lane * 2]);
    float2 bv = *(const float2*)&b[lane * 2];
    float2 v;
    v.x = fmaxf(fmaf(acc0.x + hs.x, di, bv.x), 0.f);
    v.y = fmaxf(fmaf(acc0.y + hs.y, di, bv.y), 0.f);
    *(float2*)&out[(size_t)node * 128 + lane * 2] = v;
}

// ---------- pool: one block per graph, bounds by binary search, no atomics ----------
__global__ __launch_bounds__(256) void k_pool(const float* __restrict__ out,
                                              const int* __restrict__ batch,
                                              float* __restrict__ pool, int N, int G) {
    __shared__ float sacc[256];
    __shared__ int bounds[2];
    int g = blockIdx.x;
    int t = threadIdx.x;
    if (t < 2) {
        int target = g + t;               // first index with batch[idx] >= target
        int lo = 0, hi = N;
        while (lo < hi) {
            int mid = (lo + hi) >> 1;
            if (batch[mid] < target) lo = mid + 1; else hi = mid;
        }
        bounds[t] = lo;
    }
    __syncthreads();
    int lo = bounds[0], hi = bounds[1];
    int d = t & 127, r = t >> 7;
    float s = 0.f;
    for (int n = lo + r; n < hi; n += 2)
        s += out[(size_t)n * 128 + d];
    sacc[t] = s;
    __syncthreads();
    if (t < 128) {
        float tot = sacc[t] + sacc[t + 128];
        pool[(size_t)g * 128 + t] = tot / fmaxf((float)(hi - lo), 1.0f);
    }
}

extern "C" void kernel_launch(void* const* d_in, const int* in_sizes, int n_in,
                              void* d_out, int out_size, void* d_ws, size_t ws_size,
                              hipStream_t stream) {
    const float* x     = (const float*)d_in[0];
    const int*   ei    = (const int*)d_in[1];
    const float* ew    = (const float*)d_in[2];
    const int*   batch = (const int*)d_in[3];
    const float* W     = (const float*)d_in[4];
    const float* b     = (const float*)d_in[5];

    int N = in_sizes[3];                  // 50000
    int E = in_sizes[2];                  // 800000
    int G = (out_size - N * 128) / 128;   // 500
    int M = N * REPS;
    int nb1 = (M + 255) / 256;

    float* out  = (float*)d_out;
    float* pool = out + (size_t)N * 128;

    // workspace layout (~26 MB)
    f16*    hh     = (f16*)d_ws;                        // N*128 f16   (12.8 MB)
    int2*   srcval = (int2*)(hh + (size_t)N * 128);     // E int2      (6.4 MB)
    float*  dinv   = (float*)(srcval + E);              // N f
    int*    cnt4   = (int*)(dinv + N);                  // 8N i        (1.6 MB)
    int*    rp4    = cnt4 + M;                          // 8N+1 i      (1.6 MB)
    int*    bsum   = rp4 + M + 1;                       // nb1 i
    int*    pos    = bsum + nb1;                        // E i         (3.2 MB)
    f16*    Wt     = (f16*)(pos + E);                   // 128*128 f16 (32 KB)

    int M4  = M / 4;                       // int4 chunks to zero
    int nzb = (M4 + 255) / 256;
    k_init<<<nzb + 16, 256, 0, stream>>>(cnt4, M4, nzb, W, Wt);
    k_count_pos<<<(E + 255) / 256, 256, 0, stream>>>(ei, cnt4, pos, E, N);
    k_scan1<<<nb1, 256, 0, stream>>>(cnt4, rp4, bsum, M, N);
    k_scan3<<<nb1, 256, 0, stream>>>(rp4, bsum, M, E);
    k_fill<<<(E + 255) / 256, 256, 0, stream>>>(ei, ew, rp4, pos, srcval, E);
    k_deg_csr<<<(N + 255) / 256, 256, 0, stream>>>(rp4, srcval, dinv, N);
    k_gemm<<<(N + 127) / 128, 256, 0, stream>>>(x, Wt, dinv, hh, N);
    k_aggregate<<<(N + 3) / 4, 256, 0, stream>>>(srcval, rp4, (const __half*)hh, dinv, b, out, N);
    k_pool<<<G, 256, 0, stream>>>(out, batch, pool, N, G);
}